// Round 12
// baseline (4844.342 us; speedup 1.0000x reference)
//
#include <hip/hip_runtime.h>
#include <math.h>

#define HW 65536

typedef unsigned short ushortt;
typedef __attribute__((ext_vector_type(8))) short short8;
typedef __attribute__((ext_vector_type(16))) float floatx16;

__device__ __forceinline__ int refl(int i) {
    return i < 0 ? -i : (i > 255 ? 510 - i : i);
}

__device__ __forceinline__ ushortt f2bf(float f) {
    unsigned u = __builtin_bit_cast(unsigned, f);
    u += 0x7fffu + ((u >> 16) & 1u);   // RNE
    return (ushortt)(u >> 16);
}

__device__ __forceinline__ float bf2f(ushortt u) {
    unsigned x = ((unsigned)u) << 16;
    return __builtin_bit_cast(float, x);
}

__device__ __forceinline__ float bf2f_s(short u) {
    unsigned x = ((unsigned)(ushortt)u) << 16;
    return __builtin_bit_cast(float, x);
}

// ---- init: w1 passthrough + zero loss slot + zero SE means accumulator ----
__global__ __launch_bounds__(256) void k_init(const float* __restrict__ w1, float* __restrict__ out,
                                              float* __restrict__ means) {
    int idx = blockIdx.x * 256 + threadIdx.x;
    if (idx < 14641) out[131072 + idx] = w1[idx];
    if (idx == 14641) out[145713] = 0.f;
    if (idx < 256) means[idx] = 0.f;
}

// ---- Wx1 = conv11x11 (Cin=1 -> 121) v2: LDS tile + register window, all oc
//      per block. 121 FMAs/oc from registers; weights via uniform loads. ----
__global__ __launch_bounds__(256, 2) void k_conv11_1toC(const float* __restrict__ in,
                                                        const float* __restrict__ w,
                                                        const float* __restrict__ bias,
                                                        ushortt* __restrict__ out) {
    __shared__ float ts[26 * 26];
    int tid = threadIdx.x;
    int bx = blockIdx.x, b = blockIdx.y;
    int y0 = (bx >> 4) * 16, x0 = (bx & 15) * 16;
    for (int idx = tid; idx < 676; idx += 256) {
        int r = idx / 26, c = idx - r * 26;
        ts[idx] = in[(b << 16) + (refl(y0 + r - 5) << 8) + refl(x0 + c - 5)];
    }
    __syncthreads();
    int tX = tid & 15, tY = tid >> 4;
    float win[121];
    #pragma unroll
    for (int ky = 0; ky < 11; ++ky)
        #pragma unroll
        for (int kx = 0; kx < 11; ++kx)
            win[ky * 11 + kx] = ts[(tY + ky) * 26 + tX + kx];
    int obase = ((b * 121) << 16) + ((y0 + tY) << 8) + x0 + tX;
    #pragma unroll 1
    for (int oc = 0; oc < 121; ++oc) {
        float acc = bias[oc];
        const float* wr = w + oc * 121;
        #pragma unroll
        for (int t = 0; t < 121; ++t) acc += wr[t] * win[t];
        out[obase + (oc << 16)] = f2bf(acc);
    }
}

// ---- weight repack (11x11), BOTH layouts in one pass:
//      outa = forward w2, outb = rot180(w2)^T; Wfrag[kc][s(124)][mt][lane][j] ----
__global__ __launch_bounds__(256) void k_wrepack2(const float* __restrict__ w,
                                                  short* __restrict__ outa,
                                                  short* __restrict__ outb) {
    int idx = blockIdx.x * 256 + threadIdx.x;
    if (idx >= 2031616) return;   // 8*124*4*64*8
    int j    = idx & 7;
    int lane = (idx >> 3) & 63;
    int mt   = (idx >> 9) & 3;
    int sk   = idx >> 11;         // kc*124 + s
    int kc   = sk / 124;
    int s    = sk - kc * 124;
    int oc = mt * 32 + (lane & 31);
    int ic = kc * 16 + (lane >> 5) * 8 + j;
    float va = 0.f, vb = 0.f;
    if (s < 121 && oc < 121 && ic < 121) {
        int ky = s / 11, kx = s - ky * 11;
        va = w[((oc * 121 + ic) * 11 + ky) * 11 + kx];
        vb = w[((ic * 121 + oc) * 11 + (10 - ky)) * 11 + (10 - kx)];
    }
    outa[idx] = (short)f2bf(va);
    outb[idx] = (short)f2bf(vb);
}

// ---- weight repack (3x3, 122 ic): Wfrag[s][kc][mt][lane][j] bf16 ----
__global__ __launch_bounds__(256) void k_wrepack3(const float* __restrict__ w,
                                                  short* __restrict__ outw) {
    int idx = blockIdx.x * 256 + threadIdx.x;
    if (idx >= 147456) return;    // 9 << 14
    int j    = idx & 7;
    int lane = (idx >> 3) & 63;
    int mt   = (idx >> 9) & 3;
    int kc   = (idx >> 11) & 7;
    int s    = idx >> 14;
    int oc = mt * 32 + (lane & 31);
    int ic = kc * 16 + (lane >> 5) * 8 + j;
    float v = 0.f;
    if (oc < 121 && ic < 122)
        v = w[(oc * 122 + ic) * 9 + s];
    outw[idx] = (short)f2bf(v);
}

// ---- weight repack thw ----
__global__ __launch_bounds__(256) void k_wrepack_thw(const float* __restrict__ thw,
                                                     short* __restrict__ outw) {
    int idx = blockIdx.x * 256 + threadIdx.x;
    if (idx >= 126976) return;    // 31*8*64*8
    int j    = idx & 7;
    int lane = (idx >> 3) & 63;
    int kc   = (idx >> 9) & 7;
    int g    = idx >> 12;
    int m = lane & 31, kg = lane >> 5;
    int k = kc * 16 + kg * 8 + j;
    int sel = m >> 3, mc = m & 7;
    int ch = g * 8 + mc;
    float v = 0.f;
    if (sel < 3 && ch < 244 && k < 122)
        v = thw[(sel * 244 + ch) * 122 + k];
    outw[idx] = (short)f2bf(v);
}

#define ADV11(cb, kx) { if (kx == 10) { kx = 0; cb += 384; } else { ++kx; cb += 24; } }
#define MFMA8(W0, W1, W2, W3, V0, V1) { \
    acc[0] = __builtin_amdgcn_mfma_f32_32x32x16_bf16(W0, V0, acc[0], 0, 0, 0); \
    acc[1] = __builtin_amdgcn_mfma_f32_32x32x16_bf16(W0, V1, acc[1], 0, 0, 0); \
    acc[2] = __builtin_amdgcn_mfma_f32_32x32x16_bf16(W1, V0, acc[2], 0, 0, 0); \
    acc[3] = __builtin_amdgcn_mfma_f32_32x32x16_bf16(W1, V1, acc[3], 0, 0, 0); \
    acc[4] = __builtin_amdgcn_mfma_f32_32x32x16_bf16(W2, V0, acc[4], 0, 0, 0); \
    acc[5] = __builtin_amdgcn_mfma_f32_32x32x16_bf16(W2, V1, acc[5], 0, 0, 0); \
    acc[6] = __builtin_amdgcn_mfma_f32_32x32x16_bf16(W3, V0, acc[6], 0, 0, 0); \
    acc[7] = __builtin_amdgcn_mfma_f32_32x32x16_bf16(W3, V1, acc[7], 0, 0, 0); }

// ---- MFMA 11x11 conv 121->121 (v11/v15 proven structure: 16KB weight groups,
//      global_load_lds DMA into double buffer, __syncthreads-only sync) ----
__global__ __launch_bounds__(256, 2) void k_conv11_mfma(const ushortt* __restrict__ in,
                                                        const short* __restrict__ Wf,
                                                        const float* __restrict__ bias,
                                                        float scale,
                                                        const ushortt* __restrict__ cmp,
                                                        ushortt* __restrict__ out,
                                                        float* __restrict__ lossout) {
    __shared__ __align__(16) ushortt lt[26 * 26 * 24];   // 32,448 B
    __shared__ __align__(16) short8 wbuf[2][1024];       // 32,768 B
    int tid = threadIdx.x;
    int lane = tid & 63, wv = tid >> 6;
    int l15 = lane & 15, sub = (lane >> 4) & 1, kg = lane >> 5;
    int bx = blockIdx.x, b = blockIdx.y;
    int y0 = (bx >> 4) * 16, x0 = (bx & 15) * 16;
    bool interior = (y0 != 0) && (y0 != 240) && (x0 != 0) && (x0 != 240);

    floatx16 acc[8];
    #pragma unroll
    for (int i = 0; i < 8; ++i)
        #pragma unroll
        for (int e = 0; e < 16; ++e) acc[i][e] = 0.f;

    const short8* Wf8 = (const short8*)Wf;
    int wbase = wv * 256;     // this wave's contiguous 4 KiB quarter of a 16 KiB group

    for (int kc = 0; kc < 8; ++kc) {
        __syncthreads();     // prev chunk's lt & wbuf reads done
        // stage input tile
        if (interior) {
            for (int pi = tid; pi < 416; pi += 256) {
                int ic = pi / 26, r = pi - ic * 26;
                int gic = kc * 16 + ic;
                ushortt* dst = &lt[r * 26 * 24 + ic];
                if (gic < 121) {
                    const ushortt* src = in + ((b * 121 + gic) << 16) + ((y0 + r - 5) << 8) + x0 - 8;
                    #pragma unroll
                    for (int sg = 0; sg < 4; ++sg) {
                        short8 v = *(const short8*)&src[sg * 8];
                        #pragma unroll
                        for (int q = 0; q < 8; ++q) {
                            int c = sg * 8 + q - 3;
                            if ((unsigned)c < 26u) dst[c * 24] = (ushortt)v[q];
                        }
                    }
                } else {
                    #pragma unroll
                    for (int c = 0; c < 26; ++c) dst[c * 24] = 0;
                }
            }
        } else {
            for (int idx = tid; idx < 26 * 26 * 16; idx += 256) {
                int ic = idx / 676, pix = idx - ic * 676;
                int r = pix / 26, c = pix - r * 26;
                int gic = kc * 16 + ic;
                ushortt v = 0;
                if (gic < 121) {
                    int gy = refl(y0 + r - 5), gx = refl(x0 + c - 5);
                    v = in[((b * 121 + gic) << 16) + (gy << 8) + gx];
                }
                lt[pix * 24 + ic] = v;
            }
        }
        // DMA weight group 0 of this kc into wbuf[0]
        {
            const short8* s = Wf8 + kc * 31744 + wbase + lane;   // 31744 = 124*256
            #pragma unroll
            for (int j = 0; j < 4; ++j)
                __builtin_amdgcn_global_load_lds(
                    (const __attribute__((address_space(1))) void*)(s + j * 64),
                    (__attribute__((address_space(3))) void*)&wbuf[0][wbase + j * 64],
                    16, 0, 0);
        }
        __syncthreads();     // lt ready + group-0 DMA landed (vmcnt(0) in syncthreads)

        int cur = 0;
        int cb = ((4 * wv + sub) * 26 + l15) * 24 + kg * 8;
        int kx = 0;
        #pragma unroll 1
        for (int g = 0; g < 31; ++g) {
            if (g < 30) {
                const short8* s = Wf8 + kc * 31744 + (g + 1) * 1024 + wbase + lane;
                #pragma unroll
                for (int j = 0; j < 4; ++j)
                    __builtin_amdgcn_global_load_lds(
                        (const __attribute__((address_space(1))) void*)(s + j * 64),
                        (__attribute__((address_space(3))) void*)&wbuf[cur ^ 1][wbase + j * 64],
                        16, 0, 0);
            }
            const short8* wb = wbuf[cur];
            #pragma unroll
            for (int tt = 0; tt < 4; ++tt) {
                short8 A0 = wb[tt * 256 + lane];
                short8 A1 = wb[tt * 256 + 64 + lane];
                short8 A2 = wb[tt * 256 + 128 + lane];
                short8 A3 = wb[tt * 256 + 192 + lane];
                short8 B0 = *(const short8*)&lt[cb];
                short8 B1 = *(const short8*)&lt[cb + 1248];
                MFMA8(A0, A1, A2, A3, B0, B1);
                ADV11(cb, kx);
            }
            __syncthreads();
            cur ^= 1;
        }
    }
    if (!cmp) {
        #pragma unroll
        for (int mt = 0; mt < 4; ++mt) {
            #pragma unroll
            for (int e = 0; e < 16; ++e) {
                int oc = mt * 32 + (e & 3) + 8 * (e >> 2) + 4 * kg;
                if (oc < 121) {
                    float bv = bias ? bias[oc] : 0.f;
                    #pragma unroll
                    for (int t = 0; t < 2; ++t) {
                        int y = y0 + 4 * wv + 2 * t + sub, x = x0 + l15;
                        out[((b * 121 + oc) << 16) + (y << 8) + x] = f2bf((acc[mt * 2 + t][e] + bv) * scale);
                    }
                }
            }
        }
    } else {
        float lsum = 0.f;
        #pragma unroll
        for (int mt = 0; mt < 4; ++mt) {
            #pragma unroll
            for (int e = 0; e < 16; ++e) {
                int oc = mt * 32 + (e & 3) + 8 * (e >> 2) + 4 * kg;
                if (oc < 121) {
                    float bv = bias ? bias[oc] : 0.f;
                    #pragma unroll
                    for (int t = 0; t < 2; ++t) {
                        int y = y0 + 4 * wv + 2 * t + sub, x = x0 + l15;
                        float res = (acc[mt * 2 + t][e] + bv) * scale;
                        float df = res - bf2f(cmp[((b * 121 + oc) << 16) + (y << 8) + x]);
                        lsum += df * df;
                    }
                }
            }
        }
        __syncthreads();
        float* red = (float*)lt;
        red[tid] = lsum;
        __syncthreads();
        for (int off = 128; off > 0; off >>= 1) {
            if (tid < off) red[tid] += red[tid + off];
            __syncthreads();
        }
        if (tid == 0) atomicAdd(lossout, red[0]);
    }
}

// ---- MFMA 3x3 conv 122->121 + FUSED soft-threshold epilogue:
//      z = soft(Wx, clip(conv3(out1*sey)+b, 0, 10) * sigma)  (z -> D slot) ----
__global__ __launch_bounds__(256, 2) void k_conv3_mfma(const ushortt* __restrict__ in,
                                                       const short* __restrict__ Wf,
                                                       const float* __restrict__ bias,
                                                       const float* __restrict__ sey,
                                                       const float* __restrict__ sigma,
                                                       const ushortt* __restrict__ Wx,
                                                       ushortt* __restrict__ z) {
    __shared__ __align__(16) ushortt lt[18 * 18 * 24];
    int tid = threadIdx.x;
    int lane = tid & 63, wv = tid >> 6;
    int l15 = lane & 15, sub = (lane >> 4) & 1, kg = lane >> 5;
    int bx = blockIdx.x, b = blockIdx.y;
    int y0 = (bx >> 4) * 16, x0 = (bx & 15) * 16;

    floatx16 acc[8];
    #pragma unroll
    for (int i = 0; i < 8; ++i)
        #pragma unroll
        for (int e = 0; e < 16; ++e) acc[i][e] = 0.f;

    const short8* Wf8 = (const short8*)Wf;
    for (int kc = 0; kc < 8; ++kc) {
        __syncthreads();
        for (int idx = tid; idx < 18 * 18 * 16; idx += 256) {
            int ic = idx / 324, pix = idx - ic * 324;
            int r = pix / 18, c = pix - r * 18;
            int gic = kc * 16 + ic;
            float v = 0.f;
            if (gic < 122) {
                int gy = y0 + r - 1, gx = x0 + c - 1;
                if ((unsigned)gy < 256u && (unsigned)gx < 256u)
                    v = bf2f(in[((b * 122 + gic) << 16) + (gy << 8) + gx]) * sey[b * 122 + gic];
            }
            lt[pix * 24 + ic] = f2bf(v);
        }
        __syncthreads();
        const short8* wp = Wf8 + kc * 256 + lane;
        int cb = ((4 * wv + sub) * 18 + l15) * 24 + kg * 8;
        short8 a0 = wp[0], a1 = wp[64], a2 = wp[128], a3 = wp[192];
        short8 b0 = *(const short8*)&lt[cb];
        short8 b1 = *(const short8*)&lt[cb + 864];
        int kx = 0;
        #pragma unroll 1
        for (int s = 0; s < 9; ++s) {
            short8 na0 = a0, na1 = a1, na2 = a2, na3 = a3, nb0 = b0, nb1 = b1;
            if (s < 8) {
                wp += 2048;
                if (kx == 2) { kx = 0; cb += 384; }
                else         { ++kx;  cb += 24;  }
                na0 = wp[0]; na1 = wp[64]; na2 = wp[128]; na3 = wp[192];
                nb0 = *(const short8*)&lt[cb];
                nb1 = *(const short8*)&lt[cb + 864];
            }
            acc[0] = __builtin_amdgcn_mfma_f32_32x32x16_bf16(a0, b0, acc[0], 0, 0, 0);
            acc[1] = __builtin_amdgcn_mfma_f32_32x32x16_bf16(a0, b1, acc[1], 0, 0, 0);
            acc[2] = __builtin_amdgcn_mfma_f32_32x32x16_bf16(a1, b0, acc[2], 0, 0, 0);
            acc[3] = __builtin_amdgcn_mfma_f32_32x32x16_bf16(a1, b1, acc[3], 0, 0, 0);
            acc[4] = __builtin_amdgcn_mfma_f32_32x32x16_bf16(a2, b0, acc[4], 0, 0, 0);
            acc[5] = __builtin_amdgcn_mfma_f32_32x32x16_bf16(a2, b1, acc[5], 0, 0, 0);
            acc[6] = __builtin_amdgcn_mfma_f32_32x32x16_bf16(a3, b0, acc[6], 0, 0, 0);
            acc[7] = __builtin_amdgcn_mfma_f32_32x32x16_bf16(a3, b1, acc[7], 0, 0, 0);
            a0 = na0; a1 = na1; a2 = na2; a3 = na3; b0 = nb0; b1 = nb1;
        }
    }
    // fused epilogue: c = clip(acc+b); z = soft(Wx, c*sigma)
    float sg[2];
    #pragma unroll
    for (int t = 0; t < 2; ++t)
        sg[t] = sigma[(b << 16) + ((y0 + 4 * wv + 2 * t + sub) << 8) + x0 + l15];
    #pragma unroll
    for (int mt = 0; mt < 4; ++mt) {
        #pragma unroll
        for (int e = 0; e < 16; ++e) {
            int oc = mt * 32 + (e & 3) + 8 * (e >> 2) + 4 * kg;
            if (oc < 121) {
                float bv = bias[oc];
                #pragma unroll
                for (int t = 0; t < 2; ++t) {
                    int y = y0 + 4 * wv + 2 * t + sub, x = x0 + l15;
                    float res = fminf(fmaxf(acc[mt * 2 + t][e] + bv, 0.f), 10.f);
                    float thr = res * sg[t];
                    int off = ((b * 121 + oc) << 16) + (y << 8) + x;
                    float xv = bf2f(Wx[off]);
                    float r = xv > thr ? xv - thr : (xv < -thr ? xv + thr : 0.f);
                    z[off] = f2bf(r);
                }
            }
        }
    }
}

// ---- FSAS v11: pipelined + row-based depthwise ----
__global__ __launch_bounds__(256, 3) void k_fsas_patch(const float* __restrict__ input,
                                                       const ushortt* __restrict__ Wx,
                                                       const float* __restrict__ n1w,
                                                       const float* __restrict__ n1b,
                                                       const short* __restrict__ thwf,
                                                       const float* __restrict__ tdw,
                                                       ushortt* __restrict__ o_out,
                                                       ushortt* __restrict__ v_out) {
    __shared__ __align__(16) ushortt xnb[100 * 136];     // 27,200 B
    __shared__ __align__(16) float h_lds[2][24 * 100];   // 19,200 B
    __shared__ __align__(16) float qb[8 * 64];           //  2,048 B
    __shared__ __align__(16) float kbd[8 * 8 * 20];      //  5,120 B
    int patch = blockIdx.x, b = blockIdx.y;
    int py0 = (patch >> 5) << 3, px0 = (patch & 31) << 3;
    int tid = threadIdx.x;
    int lane = tid & 63, wvv = tid >> 6;
    int l31 = lane & 31, kg = lane >> 5;

    for (int idx = tid; idx < 12200; idx += 256) {
        int c = idx / 100, pos = idx - c * 100;
        int gy = py0 + pos / 10 - 1, gx = px0 + pos % 10 - 1;
        ushortt v = 0;
        if ((unsigned)gy < 256u && (unsigned)gx < 256u) {
            int pix = (gy << 8) + gx;
            v = (c == 0) ? f2bf(input[(b << 16) + pix]) : Wx[((b * 121 + c - 1) << 16) + pix];
        }
        xnb[pos * 136 + c] = v;
    }
    for (int idx = tid; idx < 600; idx += 256) {
        int pos = idx / 6, c = 122 + (idx - (idx / 6) * 6);
        xnb[pos * 136 + c] = 0;
    }
    __syncthreads();
    if (tid < 100) {
        int pos = tid;
        int gy = py0 + pos / 10 - 1, gx = px0 + pos % 10 - 1;
        if ((unsigned)gy < 256u && (unsigned)gx < 256u) {
            float s = 0.f, ss = 0.f;
            for (int c = 0; c < 122; ++c) { float v = bf2f(xnb[pos * 136 + c]); s += v; ss += v * v; }
            float mu = s * (1.f / 122.f);
            float rs = rsqrtf(fmaxf(ss * (1.f / 122.f) - mu * mu, 0.f) + 1e-5f);
            for (int c = 0; c < 122; ++c) {
                float v = (bf2f(xnb[pos * 136 + c]) - mu) * rs * n1w[c] + n1b[c];
                xnb[pos * 136 + c] = f2bf(v);
            }
        }
    }
    __syncthreads();

    int p = wvv * 32 + l31;
    int pe = p < 100 ? p : 0;
    short8 bfr[8];
    #pragma unroll
    for (int kc = 0; kc < 8; ++kc)
        bfr[kc] = *(const short8*)&xnb[pe * 136 + kc * 16 + kg * 8];

    const short8* Af = (const short8*)thwf;
    floatx16 acc;

    int dm = tid >> 3, dpy = tid & 7;
    int dsel = dm >> 3, dcl = dm & 7;

    #pragma unroll 1
    for (int g = 0; g <= 31; ++g) {
        if (g < 31) {
            #pragma unroll
            for (int e = 0; e < 16; ++e) acc[e] = 0.f;
            #pragma unroll
            for (int kc = 0; kc < 8; ++kc) {
                short8 a = Af[(g * 8 + kc) * 64 + lane];
                acc = __builtin_amdgcn_mfma_f32_32x32x16_bf16(a, bfr[kc], acc, 0, 0, 0);
            }
        }
        if (g >= 1 && tid < 192) {
            int gp = g - 1;
            int ch = gp * 8 + dcl;
            if (ch < 244) {
                const float* td = tdw + (dsel * 244 + ch) * 9;
                float w0 = td[0], w1 = td[1], w2 = td[2], w3 = td[3], w4 = td[4],
                      w5 = td[5], w6 = td[6], w7 = td[7], w8 = td[8];
                const float* hrow = &h_lds[gp & 1][dm * 100 + dpy * 10];
                float r[3][10];
                #pragma unroll
                for (int dy = 0; dy < 3; ++dy)
                    #pragma unroll
                    for (int k = 0; k < 5; ++k) {
                        float2 t = *(const float2*)&hrow[dy * 10 + k * 2];
                        r[dy][k * 2] = t.x; r[dy][k * 2 + 1] = t.y;
                    }
                float o[8];
                #pragma unroll
                for (int px = 0; px < 8; ++px)
                    o[px] = w0 * r[0][px] + w1 * r[0][px + 1] + w2 * r[0][px + 2]
                          + w3 * r[1][px] + w4 * r[1][px + 1] + w5 * r[1][px + 2]
                          + w6 * r[2][px] + w7 * r[2][px + 1] + w8 * r[2][px + 2];
                float4 v0, v1;
                v0.x = o[0]; v0.y = o[1]; v0.z = o[2]; v0.w = o[3];
                v1.x = o[4]; v1.y = o[5]; v1.z = o[6]; v1.w = o[7];
                if (dsel == 0) {
                    *(float4*)&qb[dcl * 64 + dpy * 8]     = v0;
                    *(float4*)&qb[dcl * 64 + dpy * 8 + 4] = v1;
                } else if (dsel == 1) {
                    float* kr = &kbd[(dcl * 8 + dpy) * 20];
                    *(float4*)&kr[0]  = v0;
                    *(float4*)&kr[4]  = v1;
                    *(float4*)&kr[8]  = v0;
                    *(float4*)&kr[12] = v1;
                } else {
                    uint4 pk;
                    pk.x = (unsigned)f2bf(o[0]) | ((unsigned)f2bf(o[1]) << 16);
                    pk.y = (unsigned)f2bf(o[2]) | ((unsigned)f2bf(o[3]) << 16);
                    pk.z = (unsigned)f2bf(o[4]) | ((unsigned)f2bf(o[5]) << 16);
                    pk.w = (unsigned)f2bf(o[6]) | ((unsigned)f2bf(o[7]) << 16);
                    *(uint4*)&v_out[((size_t)(b * 244 + ch) << 16) + ((py0 + dpy) << 8) + px0] = pk;
                }
            }
        }
        if (g < 31 && p < 100) {
            #pragma unroll
            for (int e = 0; e < 16; ++e) {
                int m = (e & 3) + 8 * (e >> 2) + 4 * kg;
                if (m < 24) h_lds[g & 1][m * 100 + p] = acc[e];
            }
        }
        __syncthreads();
        if (g >= 1) {
            int gp = g - 1;
            int cl = tid >> 5, u = (tid >> 2) & 7, ih = tid & 3;
            float ov[8];
            #pragma unroll
            for (int v = 0; v < 8; ++v) ov[v] = 0.f;
            #pragma unroll
            for (int ii = 0; ii < 2; ++ii) {
                int i = ih * 2 + ii;
                const float* qr = &qb[cl * 64 + i * 8];
                float q[8];
                *(float4*)q       = *(const float4*)qr;
                *(float4*)(q + 4) = *(const float4*)(qr + 4);
                const float* kr = &kbd[(cl * 8 + ((u - i) & 7)) * 20];
                float kk[16];
                *(float4*)kk        = *(const float4*)kr;
                *(float4*)(kk + 4)  = *(const float4*)(kr + 4);
                *(float4*)(kk + 8)  = *(const float4*)(kr + 8);
                *(float4*)(kk + 12) = *(const float4*)(kr + 12);
                #pragma unroll
                for (int j = 0; j < 8; ++j)
                    #pragma unroll
                    for (int v = 0; v < 8; ++v)
                        ov[v] += q[j] * kk[v + 8 - j];
            }
            #pragma unroll
            for (int v = 0; v < 8; ++v) {
                ov[v] += __shfl_xor(ov[v], 1);
                ov[v] += __shfl_xor(ov[v], 2);
            }
            int ch = gp * 8 + cl;
            if (ih == 0 && ch < 244) {
                uint4 pk;
                pk.x = (unsigned)f2bf(ov[0]) | ((unsigned)f2bf(ov[1]) << 16);
                pk.y = (unsigned)f2bf(ov[2]) | ((unsigned)f2bf(ov[3]) << 16);
                pk.z = (unsigned)f2bf(ov[4]) | ((unsigned)f2bf(ov[5]) << 16);
                pk.w = (unsigned)f2bf(ov[6]) | ((unsigned)f2bf(ov[7]) << 16);
                *(uint4*)&o_out[((size_t)((b * 244 + ch)) << 16) + ((py0 + u) << 8) + px0] = pk;
            }
        }
        __syncthreads();
    }
}

// ---- a = v * LN_c(o) (in place over v) v2: 2 px/thread, 256 blocks (4x TLP) ----
__global__ __launch_bounds__(256) void k_a_ln(const ushortt* __restrict__ o,
                                              ushortt* __restrict__ v,
                                              const float* __restrict__ fnw,
                                              const float* __restrict__ fnb) {
    int t = blockIdx.x * 256 + threadIdx.x;   // t < 65536
    int p2 = t * 2;
    int b = p2 >> 16, pix = p2 & 65535;
    float s0 = 0.f, s1 = 0.f, ss0 = 0.f, ss1 = 0.f;
    for (int c = 0; c < 244; ++c) {
        unsigned u = *(const unsigned*)&o[((b * 244 + c) << 16) + pix];
        float f0 = bf2f((ushortt)(u & 0xffffu));
        float f1 = bf2f((ushortt)(u >> 16));
        s0 += f0; ss0 += f0 * f0;
        s1 += f1; ss1 += f1 * f1;
    }
    float mu0 = s0 * (1.f / 244.f), mu1 = s1 * (1.f / 244.f);
    float rs0 = rsqrtf(fmaxf(ss0 * (1.f / 244.f) - mu0 * mu0, 0.f) + 1e-5f);
    float rs1 = rsqrtf(fmaxf(ss1 * (1.f / 244.f) - mu1 * mu1, 0.f) + 1e-5f);
    for (int c = 0; c < 244; ++c) {
        int base = ((b * 244 + c) << 16) + pix;
        unsigned uo = *(const unsigned*)&o[base];
        unsigned uv = *(const unsigned*)&v[base];
        float w = fnw[c], bb = fnb[c];
        float t0 = (bf2f((ushortt)(uo & 0xffffu)) - mu0) * rs0 * w + bb;
        float t1 = (bf2f((ushortt)(uo >> 16)) - mu1) * rs1 * w + bb;
        float r0 = bf2f((ushortt)(uv & 0xffffu)) * t0;
        float r1 = bf2f((ushortt)(uv >> 16)) * t1;
        *(unsigned*)&v[base] = (unsigned)f2bf(r0) | ((unsigned)f2bf(r1) << 16);
    }
}

// ---- out1(bf16) = cat + pw(1x1) @ a ; FUSED SE partial channel sums ----
__global__ __launch_bounds__(256) void k_pw_res(const ushortt* __restrict__ a,
                                                const float* __restrict__ pw,
                                                const float* __restrict__ input,
                                                const ushortt* __restrict__ Wx,
                                                ushortt* __restrict__ out1,
                                                float* __restrict__ means) {
    __shared__ float pws[8 * 244];
    __shared__ float redm[32];
    int g = blockIdx.y, b = blockIdx.z;
    int tid = threadIdx.x;
    for (int i = tid; i < 8 * 244; i += 256) {
        int j = i / 244, c = i - j * 244;
        int oc = g * 8 + j;
        pws[i] = (oc < 122) ? pw[oc * 244 + c] : 0.f;
    }
    __syncthreads();
    int p = (blockIdx.x * 256 + tid) * 8;
    float acc[8][8];
    #pragma unroll
    for (int j = 0; j < 8; ++j)
        #pragma unroll
        for (int q = 0; q < 8; ++q) acc[j][q] = 0.f;
    for (int c = 0; c < 244; ++c) {
        short8 a8 = *(const short8*)&a[((b * 244 + c) << 16) + p];
        float av[8];
        #pragma unroll
        for (int q = 0; q < 8; ++q) av[q] = bf2f_s(a8[q]);
        #pragma unroll
        for (int j = 0; j < 8; ++j) {
            float w = pws[j * 244 + c];
            #pragma unroll
            for (int q = 0; q < 8; ++q) acc[j][q] += w * av[q];
        }
    }
    float ps[8];
    #pragma unroll
    for (int j = 0; j < 8; ++j) ps[j] = 0.f;
    #pragma unroll
    for (int j = 0; j < 8; ++j) {
        int oc = g * 8 + j;
        if (oc < 122) {
            float cat[8];
            if (oc == 0) {
                const float* src = input + (b << 16) + p;
                float4 c0 = *(const float4*)src;
                float4 c1 = *(const float4*)(src + 4);
                cat[0] = c0.x; cat[1] = c0.y; cat[2] = c0.z; cat[3] = c0.w;
                cat[4] = c1.x; cat[5] = c1.y; cat[6] = c1.z; cat[7] = c1.w;
            } else {
                short8 w8 = *(const short8*)&Wx[((b * 121 + oc - 1) << 16) + p];
                #pragma unroll
                for (int q = 0; q < 8; ++q) cat[q] = bf2f_s(w8[q]);
            }
            short8 r8;
            #pragma unroll
            for (int q = 0; q < 8; ++q) {
                float ov = cat[q] + acc[j][q];
                ps[j] += ov;
                r8[q] = (short)f2bf(ov);
            }
            *(short8*)&out1[((b * 122 + oc) << 16) + p] = r8;
        }
    }
    // wave reduce then one atomic per (block, oc)
    int lane = tid & 63, wvv = tid >> 6;
    #pragma unroll
    for (int j = 0; j < 8; ++j) {
        ps[j] += __shfl_xor(ps[j], 1);
        ps[j] += __shfl_xor(ps[j], 2);
        ps[j] += __shfl_xor(ps[j], 4);
        ps[j] += __shfl_xor(ps[j], 8);
        ps[j] += __shfl_xor(ps[j], 16);
        ps[j] += __shfl_xor(ps[j], 32);
    }
    if (lane == 0) {
        #pragma unroll
        for (int j = 0; j < 8; ++j) redm[wvv * 8 + j] = ps[j];
    }
    __syncthreads();
    if (tid < 8) {
        int oc = g * 8 + tid;
        if (oc < 122) {
            float s = redm[tid] + redm[8 + tid] + redm[16 + tid] + redm[24 + tid];
            atomicAdd(&means[b * 122 + oc], s);
        }
    }
}

// ---- SE: fc -> relu -> fc -> sigmoid (means holds raw sums; re-zeroes means) ----
__global__ __launch_bounds__(256) void k_se_fc(const float* __restrict__ mean,
                                               const float* __restrict__ f1,
                                               const float* __restrict__ f2,
                                               float* __restrict__ sey) {
    int b = blockIdx.x, tid = threadIdx.x;
    __shared__ float y1[7];
    if (tid < 7) {
        float s = 0.f;
        for (int c = 0; c < 122; ++c) s += f1[tid * 122 + c] * (mean[b * 122 + c] * (1.f / HW));
        y1[tid] = fmaxf(s, 0.f);
    }
    __syncthreads();
    if (tid < 122) {
        float s = 0.f;
        #pragma unroll
        for (int j = 0; j < 7; ++j) s += f2[tid * 7 + j] * y1[j];
        sey[b * 122 + tid] = 1.f / (1.f + expf(-s));
        ((float*)mean)[b * 122 + tid] = 0.f;   // ready for next tblock's accumulation
    }
}

// ---- Wt = conv11(Wt2(bf16), rot180(w1)^T)/121, 121 -> 1; tile stride 48 ----
__global__ __launch_bounds__(256) void k_wt(const ushortt* __restrict__ Wt2,
                                            const float* __restrict__ w1,
                                            float* __restrict__ out) {
    __shared__ float tile[26 * 48];
    int b = blockIdx.y;
    int ty0 = (blockIdx.x >> 4) * 16, tx0 = (blockIdx.x & 15) * 16;
    int tid = threadIdx.x;
    int tX = tid & 15, tY = tid >> 4;
    float acc = 0.f;
    for (int ic = 0; ic < 121; ++ic) {
        const ushortt* src = Wt2 + ((b * 121 + ic) << 16);
        for (int idx = tid; idx < 26 * 26; idx += 256) {
            int r = idx / 26, c = idx - r * 26;
            tile[r * 48 + c] = bf2f(src[(refl(ty0 + r - 5) << 8) + refl(tx0 + c - 5)]);
        }
        __syncthreads();
        const float* wr = w1 + ic * 121;
        #pragma unroll 1
        for (int ky = 0; ky < 11; ++ky) {
            #pragma unroll
            for (int kx = 0; kx < 11; ++kx)
                acc += wr[(10 - ky) * 11 + (10 - kx)] * tile[(tY + ky) * 48 + tX + kx];
        }
        __syncthreads();
    }
    out[(b << 16) + ((ty0 + tY) << 8) + tx0 + tX] = acc * (1.f / 121.f);
}

extern "C" void kernel_launch(void* const* d_in, const int* in_sizes, int n_in,
                              void* d_out, int out_size, void* d_ws, size_t ws_size,
                              hipStream_t stream) {
    const float* input = (const float*)d_in[0];
    const float* sigma = (const float*)d_in[1];
    const float* w1    = (const float*)d_in[2];
    const float* b1    = (const float*)d_in[3];
    const float* w2    = (const float*)d_in[4];
    const float* b2    = (const float*)d_in[5];
    const float* n1w   = (const float*)d_in[6];
    const float* n1b   = (const float*)d_in[7];
    const float* thw   = (const float*)d_in[8];
    const float* tdw   = (const float*)d_in[9];
    const float* fnw   = (const float*)d_in[10];
    const float* fnb   = (const float*)d_in[11];
    const float* pw    = (const float*)d_in[12];
    const float* se1f1 = (const float*)d_in[13];
    const float* se1f2 = (const float*)d_in[14];
    const float* se2f1 = (const float*)d_in[15];
    const float* se2f2 = (const float*)d_in[16];
    const float* c1w   = (const float*)d_in[17];
    const float* c1b   = (const float*)d_in[18];
    const float* c2w   = (const float*)d_in[19];
    const float* c2b   = (const float*)d_in[20];
    float* out = (float*)d_out;
    float* ws  = (float*)d_ws;

    const size_t T121 = 15859712, T122 = 15990784;
    float* Wx1f   = ws;
    float* bufBf  = Wx1f + T121;
    float* C      = bufBf + T121;
    float* D      = C + T122;
    float* means  = D + T122;
    float* sey    = means + 256;
    short* thwf   = (short*)(sey + 256);
    ushortt* Wx1   = (ushortt*)Wx1f;
    ushortt* bufB  = (ushortt*)bufBf;
    ushortt* o_bf  = (ushortt*)C;
    ushortt* out1_bf = (ushortt*)C;
    ushortt* temp_bf = (ushortt*)C;
    ushortt* v_bf  = (ushortt*)D;
    ushortt* z_bf  = (ushortt*)D;      // z lives in D (old c slot); v dead by then
    // park repacked weights in the dead upper halves (32 MB offset = 8M floats):
    short* WfA = (short*)(bufBf + 8388608);
    short* WfB = (short*)(Wx1f + 8388608);
    short* Wf3 = (short*)(C + 8388608);

    dim3 blk(256);
    const ushortt* UNUL = nullptr;
    float* FNUL = nullptr;

    k_init<<<dim3(58), blk, 0, stream>>>(w1, out, means);
    k_wrepack_thw<<<dim3(496), blk, 0, stream>>>(thw, thwf);
    k_conv11_1toC<<<dim3(256, 2), blk, 0, stream>>>(input, w1, b1, Wx1);
    k_wrepack2<<<dim3(7936), blk, 0, stream>>>(w2, WfA, WfB);   // both layouts, one pass

    // ---- tblock 1 ----
    k_fsas_patch<<<dim3(1024, 2), blk, 0, stream>>>(input, Wx1, n1w, n1b, thwf, tdw, o_bf, v_bf);
    k_a_ln<<<dim3(256), blk, 0, stream>>>(o_bf, v_bf, fnw, fnb);
    k_pw_res<<<dim3(32, 16, 2), blk, 0, stream>>>(v_bf, pw, input, Wx1, out1_bf, means); // out1 -> C (+SE sums)
    k_wrepack3<<<dim3(576), blk, 0, stream>>>(c1w, Wf3);
    k_se_fc<<<dim3(2), blk, 0, stream>>>(means, se1f1, se1f2, sey);
    k_conv3_mfma<<<dim3(256, 2), blk, 0, stream>>>(out1_bf, Wf3, c1b, sey, sigma, Wx1, z_bf); // z1 -> D (fused soft)
    k_conv11_mfma<<<dim3(256, 2), blk, 0, stream>>>(z_bf, WfA, b2, 1.f, UNUL, bufB, FNUL);    // Wx2

    // ---- tblock 2 ----
    k_fsas_patch<<<dim3(1024, 2), blk, 0, stream>>>(input, bufB, n1w, n1b, thwf, tdw, o_bf, v_bf);
    k_a_ln<<<dim3(256), blk, 0, stream>>>(o_bf, v_bf, fnw, fnb);
    k_pw_res<<<dim3(32, 16, 2), blk, 0, stream>>>(v_bf, pw, input, bufB, out1_bf, means);
    k_wrepack3<<<dim3(576), blk, 0, stream>>>(c2w, Wf3);
    k_se_fc<<<dim3(2), blk, 0, stream>>>(means, se2f1, se2f2, sey);
    k_conv3_mfma<<<dim3(256, 2), blk, 0, stream>>>(out1_bf, Wf3, c2b, sey, sigma, bufB, z_bf); // z2 -> D (fused soft)

    // ---- tail (WfA/WfB both built up front) ----
    k_conv11_mfma<<<dim3(256, 2), blk, 0, stream>>>(z_bf, WfB, FNUL, 1.f / 121.f, UNUL, bufB, FNUL); // Wt2
    k_wt<<<dim3(256, 2), blk, 0, stream>>>(bufB, w1, out);                                           // Wt
    k_conv11_mfma<<<dim3(256, 2), blk, 0, stream>>>(Wx1, WfA, b2, 1.f, UNUL, temp_bf, FNUL);         // temp
    k_conv11_mfma<<<dim3(256, 2), blk, 0, stream>>>(temp_bf, WfB, FNUL, 1.f / 121.f, Wx1, (ushortt*)FNUL, out + 145713); // W2loss

    (void)in_sizes; (void)n_in; (void)out_size; (void)ws_size;
}

// Round 13
// 3918.230 us; speedup vs baseline: 1.2364x; 1.2364x over previous
//
#include <hip/hip_runtime.h>
#include <math.h>

#define HW 65536

typedef unsigned short ushortt;
typedef __attribute__((ext_vector_type(8))) short short8;
typedef __attribute__((ext_vector_type(16))) float floatx16;

__device__ __forceinline__ int refl(int i) {
    return i < 0 ? -i : (i > 255 ? 510 - i : i);
}

__device__ __forceinline__ ushortt f2bf(float f) {
    unsigned u = __builtin_bit_cast(unsigned, f);
    u += 0x7fffu + ((u >> 16) & 1u);   // RNE
    return (ushortt)(u >> 16);
}

__device__ __forceinline__ float bf2f(ushortt u) {
    unsigned x = ((unsigned)u) << 16;
    return __builtin_bit_cast(float, x);
}

__device__ __forceinline__ float bf2f_s(short u) {
    unsigned x = ((unsigned)(ushortt)u) << 16;
    return __builtin_bit_cast(float, x);
}

// ---- init: w1 passthrough + zero loss slot + zero SE means accumulator ----
__global__ __launch_bounds__(256) void k_init(const float* __restrict__ w1, float* __restrict__ out,
                                              float* __restrict__ means) {
    int idx = blockIdx.x * 256 + threadIdx.x;
    if (idx < 14641) out[131072 + idx] = w1[idx];
    if (idx == 14641) out[145713] = 0.f;
    if (idx < 256) means[idx] = 0.f;
}

// ---- Wx1 = conv11x11 (Cin=1 -> 121), reflect pad, bf16 out (v18 proven) ----
__global__ __launch_bounds__(256) void k_conv11_1toC(const float* __restrict__ in,
                                                     const float* __restrict__ w,
                                                     const float* __restrict__ bias,
                                                     ushortt* __restrict__ out) {
    int p = blockIdx.x * 256 + threadIdx.x;
    int oc = blockIdx.y, b = blockIdx.z;
    int y = p >> 8, x = p & 255;
    float acc = bias[oc];
    const float* wr = w + oc * 121;
    for (int ky = 0; ky < 11; ++ky) {
        int ry = refl(y + ky - 5);
        const float* irow = in + b * HW + (ry << 8);
        #pragma unroll
        for (int kx = 0; kx < 11; ++kx) {
            int rx = refl(x + kx - 5);
            acc += wr[ky * 11 + kx] * irow[rx];
        }
    }
    out[((b * 121 + oc) << 16) + p] = f2bf(acc);
}

// ---- weight repack (11x11), BOTH layouts in one pass:
//      outa = forward w2, outb = rot180(w2)^T; Wfrag[kc][s(124)][mt][lane][j] ----
__global__ __launch_bounds__(256) void k_wrepack2(const float* __restrict__ w,
                                                  short* __restrict__ outa,
                                                  short* __restrict__ outb) {
    int idx = blockIdx.x * 256 + threadIdx.x;
    if (idx >= 2031616) return;   // 8*124*4*64*8
    int j    = idx & 7;
    int lane = (idx >> 3) & 63;
    int mt   = (idx >> 9) & 3;
    int sk   = idx >> 11;         // kc*124 + s
    int kc   = sk / 124;
    int s    = sk - kc * 124;
    int oc = mt * 32 + (lane & 31);
    int ic = kc * 16 + (lane >> 5) * 8 + j;
    float va = 0.f, vb = 0.f;
    if (s < 121 && oc < 121 && ic < 121) {
        int ky = s / 11, kx = s - ky * 11;
        va = w[((oc * 121 + ic) * 11 + ky) * 11 + kx];
        vb = w[((ic * 121 + oc) * 11 + (10 - ky)) * 11 + (10 - kx)];
    }
    outa[idx] = (short)f2bf(va);
    outb[idx] = (short)f2bf(vb);
}

// ---- weight repack (3x3, 122 ic): Wfrag[s][kc][mt][lane][j] bf16 ----
__global__ __launch_bounds__(256) void k_wrepack3(const float* __restrict__ w,
                                                  short* __restrict__ outw) {
    int idx = blockIdx.x * 256 + threadIdx.x;
    if (idx >= 147456) return;    // 9 << 14
    int j    = idx & 7;
    int lane = (idx >> 3) & 63;
    int mt   = (idx >> 9) & 3;
    int kc   = (idx >> 11) & 7;
    int s    = idx >> 14;
    int oc = mt * 32 + (lane & 31);
    int ic = kc * 16 + (lane >> 5) * 8 + j;
    float v = 0.f;
    if (oc < 121 && ic < 122)
        v = w[(oc * 122 + ic) * 9 + s];
    outw[idx] = (short)f2bf(v);
}

// ---- weight repack thw ----
__global__ __launch_bounds__(256) void k_wrepack_thw(const float* __restrict__ thw,
                                                     short* __restrict__ outw) {
    int idx = blockIdx.x * 256 + threadIdx.x;
    if (idx >= 126976) return;    // 31*8*64*8
    int j    = idx & 7;
    int lane = (idx >> 3) & 63;
    int kc   = (idx >> 9) & 7;
    int g    = idx >> 12;
    int m = lane & 31, kg = lane >> 5;
    int k = kc * 16 + kg * 8 + j;
    int sel = m >> 3, mc = m & 7;
    int ch = g * 8 + mc;
    float v = 0.f;
    if (sel < 3 && ch < 244 && k < 122)
        v = thw[(sel * 244 + ch) * 122 + k];
    outw[idx] = (short)f2bf(v);
}

#define ADV11(cb, kx) { if (kx == 10) { kx = 0; cb += 384; } else { ++kx; cb += 24; } }
#define MFMA8(W0, W1, W2, W3, V0, V1) { \
    acc[0] = __builtin_amdgcn_mfma_f32_32x32x16_bf16(W0, V0, acc[0], 0, 0, 0); \
    acc[1] = __builtin_amdgcn_mfma_f32_32x32x16_bf16(W0, V1, acc[1], 0, 0, 0); \
    acc[2] = __builtin_amdgcn_mfma_f32_32x32x16_bf16(W1, V0, acc[2], 0, 0, 0); \
    acc[3] = __builtin_amdgcn_mfma_f32_32x32x16_bf16(W1, V1, acc[3], 0, 0, 0); \
    acc[4] = __builtin_amdgcn_mfma_f32_32x32x16_bf16(W2, V0, acc[4], 0, 0, 0); \
    acc[5] = __builtin_amdgcn_mfma_f32_32x32x16_bf16(W2, V1, acc[5], 0, 0, 0); \
    acc[6] = __builtin_amdgcn_mfma_f32_32x32x16_bf16(W3, V0, acc[6], 0, 0, 0); \
    acc[7] = __builtin_amdgcn_mfma_f32_32x32x16_bf16(W3, V1, acc[7], 0, 0, 0); }

// ---- MFMA 11x11 conv 121->121 (v11/v15 proven structure: 16KB weight groups,
//      global_load_lds DMA into double buffer, __syncthreads-only sync) ----
__global__ __launch_bounds__(256, 2) void k_conv11_mfma(const ushortt* __restrict__ in,
                                                        const short* __restrict__ Wf,
                                                        const float* __restrict__ bias,
                                                        float scale,
                                                        const ushortt* __restrict__ cmp,
                                                        ushortt* __restrict__ out,
                                                        float* __restrict__ lossout) {
    __shared__ __align__(16) ushortt lt[26 * 26 * 24];   // 32,448 B
    __shared__ __align__(16) short8 wbuf[2][1024];       // 32,768 B
    int tid = threadIdx.x;
    int lane = tid & 63, wv = tid >> 6;
    int l15 = lane & 15, sub = (lane >> 4) & 1, kg = lane >> 5;
    int bx = blockIdx.x, b = blockIdx.y;
    int y0 = (bx >> 4) * 16, x0 = (bx & 15) * 16;
    bool interior = (y0 != 0) && (y0 != 240) && (x0 != 0) && (x0 != 240);

    floatx16 acc[8];
    #pragma unroll
    for (int i = 0; i < 8; ++i)
        #pragma unroll
        for (int e = 0; e < 16; ++e) acc[i][e] = 0.f;

    const short8* Wf8 = (const short8*)Wf;
    int wbase = wv * 256;     // this wave's contiguous 4 KiB quarter of a 16 KiB group

    for (int kc = 0; kc < 8; ++kc) {
        __syncthreads();     // prev chunk's lt & wbuf reads done
        // stage input tile
        if (interior) {
            for (int pi = tid; pi < 416; pi += 256) {
                int ic = pi / 26, r = pi - ic * 26;
                int gic = kc * 16 + ic;
                ushortt* dst = &lt[r * 26 * 24 + ic];
                if (gic < 121) {
                    const ushortt* src = in + ((b * 121 + gic) << 16) + ((y0 + r - 5) << 8) + x0 - 8;
                    #pragma unroll
                    for (int sg = 0; sg < 4; ++sg) {
                        short8 v = *(const short8*)&src[sg * 8];
                        #pragma unroll
                        for (int q = 0; q < 8; ++q) {
                            int c = sg * 8 + q - 3;
                            if ((unsigned)c < 26u) dst[c * 24] = (ushortt)v[q];
                        }
                    }
                } else {
                    #pragma unroll
                    for (int c = 0; c < 26; ++c) dst[c * 24] = 0;
                }
            }
        } else {
            for (int idx = tid; idx < 26 * 26 * 16; idx += 256) {
                int ic = idx / 676, pix = idx - ic * 676;
                int r = pix / 26, c = pix - r * 26;
                int gic = kc * 16 + ic;
                ushortt v = 0;
                if (gic < 121) {
                    int gy = refl(y0 + r - 5), gx = refl(x0 + c - 5);
                    v = in[((b * 121 + gic) << 16) + (gy << 8) + gx];
                }
                lt[pix * 24 + ic] = v;
            }
        }
        // DMA weight group 0 of this kc into wbuf[0]
        {
            const short8* s = Wf8 + kc * 31744 + wbase + lane;   // 31744 = 124*256
            #pragma unroll
            for (int j = 0; j < 4; ++j)
                __builtin_amdgcn_global_load_lds(
                    (const __attribute__((address_space(1))) void*)(s + j * 64),
                    (__attribute__((address_space(3))) void*)&wbuf[0][wbase + j * 64],
                    16, 0, 0);
        }
        __syncthreads();     // lt ready + group-0 DMA landed (vmcnt(0) in syncthreads)

        int cur = 0;
        int cb = ((4 * wv + sub) * 26 + l15) * 24 + kg * 8;
        int kx = 0;
        #pragma unroll 1
        for (int g = 0; g < 31; ++g) {
            if (g < 30) {
                const short8* s = Wf8 + kc * 31744 + (g + 1) * 1024 + wbase + lane;
                #pragma unroll
                for (int j = 0; j < 4; ++j)
                    __builtin_amdgcn_global_load_lds(
                        (const __attribute__((address_space(1))) void*)(s + j * 64),
                        (__attribute__((address_space(3))) void*)&wbuf[cur ^ 1][wbase + j * 64],
                        16, 0, 0);
            }
            const short8* wb = wbuf[cur];
            #pragma unroll
            for (int tt = 0; tt < 4; ++tt) {
                short8 A0 = wb[tt * 256 + lane];
                short8 A1 = wb[tt * 256 + 64 + lane];
                short8 A2 = wb[tt * 256 + 128 + lane];
                short8 A3 = wb[tt * 256 + 192 + lane];
                short8 B0 = *(const short8*)&lt[cb];
                short8 B1 = *(const short8*)&lt[cb + 1248];
                MFMA8(A0, A1, A2, A3, B0, B1);
                ADV11(cb, kx);
            }
            __syncthreads();
            cur ^= 1;
        }
    }
    if (!cmp) {
        #pragma unroll
        for (int mt = 0; mt < 4; ++mt) {
            #pragma unroll
            for (int e = 0; e < 16; ++e) {
                int oc = mt * 32 + (e & 3) + 8 * (e >> 2) + 4 * kg;
                if (oc < 121) {
                    float bv = bias ? bias[oc] : 0.f;
                    #pragma unroll
                    for (int t = 0; t < 2; ++t) {
                        int y = y0 + 4 * wv + 2 * t + sub, x = x0 + l15;
                        out[((b * 121 + oc) << 16) + (y << 8) + x] = f2bf((acc[mt * 2 + t][e] + bv) * scale);
                    }
                }
            }
        }
    } else {
        float lsum = 0.f;
        #pragma unroll
        for (int mt = 0; mt < 4; ++mt) {
            #pragma unroll
            for (int e = 0; e < 16; ++e) {
                int oc = mt * 32 + (e & 3) + 8 * (e >> 2) + 4 * kg;
                if (oc < 121) {
                    float bv = bias ? bias[oc] : 0.f;
                    #pragma unroll
                    for (int t = 0; t < 2; ++t) {
                        int y = y0 + 4 * wv + 2 * t + sub, x = x0 + l15;
                        float res = (acc[mt * 2 + t][e] + bv) * scale;
                        float df = res - bf2f(cmp[((b * 121 + oc) << 16) + (y << 8) + x]);
                        lsum += df * df;
                    }
                }
            }
        }
        __syncthreads();
        float* red = (float*)lt;
        red[tid] = lsum;
        __syncthreads();
        for (int off = 128; off > 0; off >>= 1) {
            if (tid < off) red[tid] += red[tid + off];
            __syncthreads();
        }
        if (tid == 0) atomicAdd(lossout, red[0]);
    }
}

// ---- MFMA 3x3 conv 122->121 + FUSED soft-threshold epilogue:
//      z = soft(Wx, clip(conv3(out1*sey)+b, 0, 10) * sigma)  (z -> D slot) ----
__global__ __launch_bounds__(256, 2) void k_conv3_mfma(const ushortt* __restrict__ in,
                                                       const short* __restrict__ Wf,
                                                       const float* __restrict__ bias,
                                                       const float* __restrict__ sey,
                                                       const float* __restrict__ sigma,
                                                       const ushortt* __restrict__ Wx,
                                                       ushortt* __restrict__ z) {
    __shared__ __align__(16) ushortt lt[18 * 18 * 24];
    int tid = threadIdx.x;
    int lane = tid & 63, wv = tid >> 6;
    int l15 = lane & 15, sub = (lane >> 4) & 1, kg = lane >> 5;
    int bx = blockIdx.x, b = blockIdx.y;
    int y0 = (bx >> 4) * 16, x0 = (bx & 15) * 16;

    floatx16 acc[8];
    #pragma unroll
    for (int i = 0; i < 8; ++i)
        #pragma unroll
        for (int e = 0; e < 16; ++e) acc[i][e] = 0.f;

    const short8* Wf8 = (const short8*)Wf;
    for (int kc = 0; kc < 8; ++kc) {
        __syncthreads();
        for (int idx = tid; idx < 18 * 18 * 16; idx += 256) {
            int ic = idx / 324, pix = idx - ic * 324;
            int r = pix / 18, c = pix - r * 18;
            int gic = kc * 16 + ic;
            float v = 0.f;
            if (gic < 122) {
                int gy = y0 + r - 1, gx = x0 + c - 1;
                if ((unsigned)gy < 256u && (unsigned)gx < 256u)
                    v = bf2f(in[((b * 122 + gic) << 16) + (gy << 8) + gx]) * sey[b * 122 + gic];
            }
            lt[pix * 24 + ic] = f2bf(v);
        }
        __syncthreads();
        const short8* wp = Wf8 + kc * 256 + lane;
        int cb = ((4 * wv + sub) * 18 + l15) * 24 + kg * 8;
        short8 a0 = wp[0], a1 = wp[64], a2 = wp[128], a3 = wp[192];
        short8 b0 = *(const short8*)&lt[cb];
        short8 b1 = *(const short8*)&lt[cb + 864];
        int kx = 0;
        #pragma unroll 1
        for (int s = 0; s < 9; ++s) {
            short8 na0 = a0, na1 = a1, na2 = a2, na3 = a3, nb0 = b0, nb1 = b1;
            if (s < 8) {
                wp += 2048;
                if (kx == 2) { kx = 0; cb += 384; }
                else         { ++kx;  cb += 24;  }
                na0 = wp[0]; na1 = wp[64]; na2 = wp[128]; na3 = wp[192];
                nb0 = *(const short8*)&lt[cb];
                nb1 = *(const short8*)&lt[cb + 864];
            }
            acc[0] = __builtin_amdgcn_mfma_f32_32x32x16_bf16(a0, b0, acc[0], 0, 0, 0);
            acc[1] = __builtin_amdgcn_mfma_f32_32x32x16_bf16(a0, b1, acc[1], 0, 0, 0);
            acc[2] = __builtin_amdgcn_mfma_f32_32x32x16_bf16(a1, b0, acc[2], 0, 0, 0);
            acc[3] = __builtin_amdgcn_mfma_f32_32x32x16_bf16(a1, b1, acc[3], 0, 0, 0);
            acc[4] = __builtin_amdgcn_mfma_f32_32x32x16_bf16(a2, b0, acc[4], 0, 0, 0);
            acc[5] = __builtin_amdgcn_mfma_f32_32x32x16_bf16(a2, b1, acc[5], 0, 0, 0);
            acc[6] = __builtin_amdgcn_mfma_f32_32x32x16_bf16(a3, b0, acc[6], 0, 0, 0);
            acc[7] = __builtin_amdgcn_mfma_f32_32x32x16_bf16(a3, b1, acc[7], 0, 0, 0);
            a0 = na0; a1 = na1; a2 = na2; a3 = na3; b0 = nb0; b1 = nb1;
        }
    }
    // fused epilogue: c = clip(acc+b); z = soft(Wx, c*sigma)
    float sg[2];
    #pragma unroll
    for (int t = 0; t < 2; ++t)
        sg[t] = sigma[(b << 16) + ((y0 + 4 * wv + 2 * t + sub) << 8) + x0 + l15];
    #pragma unroll
    for (int mt = 0; mt < 4; ++mt) {
        #pragma unroll
        for (int e = 0; e < 16; ++e) {
            int oc = mt * 32 + (e & 3) + 8 * (e >> 2) + 4 * kg;
            if (oc < 121) {
                float bv = bias[oc];
                #pragma unroll
                for (int t = 0; t < 2; ++t) {
                    int y = y0 + 4 * wv + 2 * t + sub, x = x0 + l15;
                    float res = fminf(fmaxf(acc[mt * 2 + t][e] + bv, 0.f), 10.f);
                    float thr = res * sg[t];
                    int off = ((b * 121 + oc) << 16) + (y << 8) + x;
                    float xv = bf2f(Wx[off]);
                    float r = xv > thr ? xv - thr : (xv < -thr ? xv + thr : 0.f);
                    z[off] = f2bf(r);
                }
            }
        }
    }
}

// ---- FSAS v11: pipelined + row-based depthwise ----
__global__ __launch_bounds__(256, 3) void k_fsas_patch(const float* __restrict__ input,
                                                       const ushortt* __restrict__ Wx,
                                                       const float* __restrict__ n1w,
                                                       const float* __restrict__ n1b,
                                                       const short* __restrict__ thwf,
                                                       const float* __restrict__ tdw,
                                                       ushortt* __restrict__ o_out,
                                                       ushortt* __restrict__ v_out) {
    __shared__ __align__(16) ushortt xnb[100 * 136];     // 27,200 B
    __shared__ __align__(16) float h_lds[2][24 * 100];   // 19,200 B
    __shared__ __align__(16) float qb[8 * 64];           //  2,048 B
    __shared__ __align__(16) float kbd[8 * 8 * 20];      //  5,120 B
    int patch = blockIdx.x, b = blockIdx.y;
    int py0 = (patch >> 5) << 3, px0 = (patch & 31) << 3;
    int tid = threadIdx.x;
    int lane = tid & 63, wvv = tid >> 6;
    int l31 = lane & 31, kg = lane >> 5;

    for (int idx = tid; idx < 12200; idx += 256) {
        int c = idx / 100, pos = idx - c * 100;
        int gy = py0 + pos / 10 - 1, gx = px0 + pos % 10 - 1;
        ushortt v = 0;
        if ((unsigned)gy < 256u && (unsigned)gx < 256u) {
            int pix = (gy << 8) + gx;
            v = (c == 0) ? f2bf(input[(b << 16) + pix]) : Wx[((b * 121 + c - 1) << 16) + pix];
        }
        xnb[pos * 136 + c] = v;
    }
    for (int idx = tid; idx < 600; idx += 256) {
        int pos = idx / 6, c = 122 + (idx - (idx / 6) * 6);
        xnb[pos * 136 + c] = 0;
    }
    __syncthreads();
    if (tid < 100) {
        int pos = tid;
        int gy = py0 + pos / 10 - 1, gx = px0 + pos % 10 - 1;
        if ((unsigned)gy < 256u && (unsigned)gx < 256u) {
            float s = 0.f, ss = 0.f;
            for (int c = 0; c < 122; ++c) { float v = bf2f(xnb[pos * 136 + c]); s += v; ss += v * v; }
            float mu = s * (1.f / 122.f);
            float rs = rsqrtf(fmaxf(ss * (1.f / 122.f) - mu * mu, 0.f) + 1e-5f);
            for (int c = 0; c < 122; ++c) {
                float v = (bf2f(xnb[pos * 136 + c]) - mu) * rs * n1w[c] + n1b[c];
                xnb[pos * 136 + c] = f2bf(v);
            }
        }
    }
    __syncthreads();

    int p = wvv * 32 + l31;
    int pe = p < 100 ? p : 0;
    short8 bfr[8];
    #pragma unroll
    for (int kc = 0; kc < 8; ++kc)
        bfr[kc] = *(const short8*)&xnb[pe * 136 + kc * 16 + kg * 8];

    const short8* Af = (const short8*)thwf;
    floatx16 acc;

    int dm = tid >> 3, dpy = tid & 7;
    int dsel = dm >> 3, dcl = dm & 7;

    #pragma unroll 1
    for (int g = 0; g <= 31; ++g) {
        if (g < 31) {
            #pragma unroll
            for (int e = 0; e < 16; ++e) acc[e] = 0.f;
            #pragma unroll
            for (int kc = 0; kc < 8; ++kc) {
                short8 a = Af[(g * 8 + kc) * 64 + lane];
                acc = __builtin_amdgcn_mfma_f32_32x32x16_bf16(a, bfr[kc], acc, 0, 0, 0);
            }
        }
        if (g >= 1 && tid < 192) {
            int gp = g - 1;
            int ch = gp * 8 + dcl;
            if (ch < 244) {
                const float* td = tdw + (dsel * 244 + ch) * 9;
                float w0 = td[0], w1 = td[1], w2 = td[2], w3 = td[3], w4 = td[4],
                      w5 = td[5], w6 = td[6], w7 = td[7], w8 = td[8];
                const float* hrow = &h_lds[gp & 1][dm * 100 + dpy * 10];
                float r[3][10];
                #pragma unroll
                for (int dy = 0; dy < 3; ++dy)
                    #pragma unroll
                    for (int k = 0; k < 5; ++k) {
                        float2 t = *(const float2*)&hrow[dy * 10 + k * 2];
                        r[dy][k * 2] = t.x; r[dy][k * 2 + 1] = t.y;
                    }
                float o[8];
                #pragma unroll
                for (int px = 0; px < 8; ++px)
                    o[px] = w0 * r[0][px] + w1 * r[0][px + 1] + w2 * r[0][px + 2]
                          + w3 * r[1][px] + w4 * r[1][px + 1] + w5 * r[1][px + 2]
                          + w6 * r[2][px] + w7 * r[2][px + 1] + w8 * r[2][px + 2];
                float4 v0, v1;
                v0.x = o[0]; v0.y = o[1]; v0.z = o[2]; v0.w = o[3];
                v1.x = o[4]; v1.y = o[5]; v1.z = o[6]; v1.w = o[7];
                if (dsel == 0) {
                    *(float4*)&qb[dcl * 64 + dpy * 8]     = v0;
                    *(float4*)&qb[dcl * 64 + dpy * 8 + 4] = v1;
                } else if (dsel == 1) {
                    float* kr = &kbd[(dcl * 8 + dpy) * 20];
                    *(float4*)&kr[0]  = v0;
                    *(float4*)&kr[4]  = v1;
                    *(float4*)&kr[8]  = v0;
                    *(float4*)&kr[12] = v1;
                } else {
                    uint4 pk;
                    pk.x = (unsigned)f2bf(o[0]) | ((unsigned)f2bf(o[1]) << 16);
                    pk.y = (unsigned)f2bf(o[2]) | ((unsigned)f2bf(o[3]) << 16);
                    pk.z = (unsigned)f2bf(o[4]) | ((unsigned)f2bf(o[5]) << 16);
                    pk.w = (unsigned)f2bf(o[6]) | ((unsigned)f2bf(o[7]) << 16);
                    *(uint4*)&v_out[((size_t)(b * 244 + ch) << 16) + ((py0 + dpy) << 8) + px0] = pk;
                }
            }
        }
        if (g < 31 && p < 100) {
            #pragma unroll
            for (int e = 0; e < 16; ++e) {
                int m = (e & 3) + 8 * (e >> 2) + 4 * kg;
                if (m < 24) h_lds[g & 1][m * 100 + p] = acc[e];
            }
        }
        __syncthreads();
        if (g >= 1) {
            int gp = g - 1;
            int cl = tid >> 5, u = (tid >> 2) & 7, ih = tid & 3;
            float ov[8];
            #pragma unroll
            for (int v = 0; v < 8; ++v) ov[v] = 0.f;
            #pragma unroll
            for (int ii = 0; ii < 2; ++ii) {
                int i = ih * 2 + ii;
                const float* qr = &qb[cl * 64 + i * 8];
                float q[8];
                *(float4*)q       = *(const float4*)qr;
                *(float4*)(q + 4) = *(const float4*)(qr + 4);
                const float* kr = &kbd[(cl * 8 + ((u - i) & 7)) * 20];
                float kk[16];
                *(float4*)kk        = *(const float4*)kr;
                *(float4*)(kk + 4)  = *(const float4*)(kr + 4);
                *(float4*)(kk + 8)  = *(const float4*)(kr + 8);
                *(float4*)(kk + 12) = *(const float4*)(kr + 12);
                #pragma unroll
                for (int j = 0; j < 8; ++j)
                    #pragma unroll
                    for (int v = 0; v < 8; ++v)
                        ov[v] += q[j] * kk[v + 8 - j];
            }
            #pragma unroll
            for (int v = 0; v < 8; ++v) {
                ov[v] += __shfl_xor(ov[v], 1);
                ov[v] += __shfl_xor(ov[v], 2);
            }
            int ch = gp * 8 + cl;
            if (ih == 0 && ch < 244) {
                uint4 pk;
                pk.x = (unsigned)f2bf(ov[0]) | ((unsigned)f2bf(ov[1]) << 16);
                pk.y = (unsigned)f2bf(ov[2]) | ((unsigned)f2bf(ov[3]) << 16);
                pk.z = (unsigned)f2bf(ov[4]) | ((unsigned)f2bf(ov[5]) << 16);
                pk.w = (unsigned)f2bf(ov[6]) | ((unsigned)f2bf(ov[7]) << 16);
                *(uint4*)&o_out[((size_t)((b * 244 + ch)) << 16) + ((py0 + u) << 8) + px0] = pk;
            }
        }
        __syncthreads();
    }
}

// ---- a = v * LN_c(o) (in place over v) v2: 2 px/thread, 256 blocks (4x TLP) ----
__global__ __launch_bounds__(256) void k_a_ln(const ushortt* __restrict__ o,
                                              ushortt* __restrict__ v,
                                              const float* __restrict__ fnw,
                                              const float* __restrict__ fnb) {
    int t = blockIdx.x * 256 + threadIdx.x;   // t < 65536
    int p2 = t * 2;
    int b = p2 >> 16, pix = p2 & 65535;
    float s0 = 0.f, s1 = 0.f, ss0 = 0.f, ss1 = 0.f;
    for (int c = 0; c < 244; ++c) {
        unsigned u = *(const unsigned*)&o[((b * 244 + c) << 16) + pix];
        float f0 = bf2f((ushortt)(u & 0xffffu));
        float f1 = bf2f((ushortt)(u >> 16));
        s0 += f0; ss0 += f0 * f0;
        s1 += f1; ss1 += f1 * f1;
    }
    float mu0 = s0 * (1.f / 244.f), mu1 = s1 * (1.f / 244.f);
    float rs0 = rsqrtf(fmaxf(ss0 * (1.f / 244.f) - mu0 * mu0, 0.f) + 1e-5f);
    float rs1 = rsqrtf(fmaxf(ss1 * (1.f / 244.f) - mu1 * mu1, 0.f) + 1e-5f);
    for (int c = 0; c < 244; ++c) {
        int base = ((b * 244 + c) << 16) + pix;
        unsigned uo = *(const unsigned*)&o[base];
        unsigned uv = *(const unsigned*)&v[base];
        float w = fnw[c], bb = fnb[c];
        float t0 = (bf2f((ushortt)(uo & 0xffffu)) - mu0) * rs0 * w + bb;
        float t1 = (bf2f((ushortt)(uo >> 16)) - mu1) * rs1 * w + bb;
        float r0 = bf2f((ushortt)(uv & 0xffffu)) * t0;
        float r1 = bf2f((ushortt)(uv >> 16)) * t1;
        *(unsigned*)&v[base] = (unsigned)f2bf(r0) | ((unsigned)f2bf(r1) << 16);
    }
}

// ---- out1(bf16) = cat + pw(1x1) @ a ; FUSED SE partial channel sums ----
__global__ __launch_bounds__(256) void k_pw_res(const ushortt* __restrict__ a,
                                                const float* __restrict__ pw,
                                                const float* __restrict__ input,
                                                const ushortt* __restrict__ Wx,
                                                ushortt* __restrict__ out1,
                                                float* __restrict__ means) {
    __shared__ float pws[8 * 244];
    __shared__ float redm[32];
    int g = blockIdx.y, b = blockIdx.z;
    int tid = threadIdx.x;
    for (int i = tid; i < 8 * 244; i += 256) {
        int j = i / 244, c = i - j * 244;
        int oc = g * 8 + j;
        pws[i] = (oc < 122) ? pw[oc * 244 + c] : 0.f;
    }
    __syncthreads();
    int p = (blockIdx.x * 256 + tid) * 8;
    float acc[8][8];
    #pragma unroll
    for (int j = 0; j < 8; ++j)
        #pragma unroll
        for (int q = 0; q < 8; ++q) acc[j][q] = 0.f;
    for (int c = 0; c < 244; ++c) {
        short8 a8 = *(const short8*)&a[((b * 244 + c) << 16) + p];
        float av[8];
        #pragma unroll
        for (int q = 0; q < 8; ++q) av[q] = bf2f_s(a8[q]);
        #pragma unroll
        for (int j = 0; j < 8; ++j) {
            float w = pws[j * 244 + c];
            #pragma unroll
            for (int q = 0; q < 8; ++q) acc[j][q] += w * av[q];
        }
    }
    float ps[8];
    #pragma unroll
    for (int j = 0; j < 8; ++j) ps[j] = 0.f;
    #pragma unroll
    for (int j = 0; j < 8; ++j) {
        int oc = g * 8 + j;
        if (oc < 122) {
            float cat[8];
            if (oc == 0) {
                const float* src = input + (b << 16) + p;
                float4 c0 = *(const float4*)src;
                float4 c1 = *(const float4*)(src + 4);
                cat[0] = c0.x; cat[1] = c0.y; cat[2] = c0.z; cat[3] = c0.w;
                cat[4] = c1.x; cat[5] = c1.y; cat[6] = c1.z; cat[7] = c1.w;
            } else {
                short8 w8 = *(const short8*)&Wx[((b * 121 + oc - 1) << 16) + p];
                #pragma unroll
                for (int q = 0; q < 8; ++q) cat[q] = bf2f_s(w8[q]);
            }
            short8 r8;
            #pragma unroll
            for (int q = 0; q < 8; ++q) {
                float ov = cat[q] + acc[j][q];
                ps[j] += ov;
                r8[q] = (short)f2bf(ov);
            }
            *(short8*)&out1[((b * 122 + oc) << 16) + p] = r8;
        }
    }
    // wave reduce then one atomic per (block, oc)
    int lane = tid & 63, wvv = tid >> 6;
    #pragma unroll
    for (int j = 0; j < 8; ++j) {
        ps[j] += __shfl_xor(ps[j], 1);
        ps[j] += __shfl_xor(ps[j], 2);
        ps[j] += __shfl_xor(ps[j], 4);
        ps[j] += __shfl_xor(ps[j], 8);
        ps[j] += __shfl_xor(ps[j], 16);
        ps[j] += __shfl_xor(ps[j], 32);
    }
    if (lane == 0) {
        #pragma unroll
        for (int j = 0; j < 8; ++j) redm[wvv * 8 + j] = ps[j];
    }
    __syncthreads();
    if (tid < 8) {
        int oc = g * 8 + tid;
        if (oc < 122) {
            float s = redm[tid] + redm[8 + tid] + redm[16 + tid] + redm[24 + tid];
            atomicAdd(&means[b * 122 + oc], s);
        }
    }
}

// ---- SE: fc -> relu -> fc -> sigmoid (means holds raw sums; re-zeroes means) ----
__global__ __launch_bounds__(256) void k_se_fc(const float* __restrict__ mean,
                                               const float* __restrict__ f1,
                                               const float* __restrict__ f2,
                                               float* __restrict__ sey) {
    int b = blockIdx.x, tid = threadIdx.x;
    __shared__ float y1[7];
    if (tid < 7) {
        float s = 0.f;
        for (int c = 0; c < 122; ++c) s += f1[tid * 122 + c] * (mean[b * 122 + c] * (1.f / HW));
        y1[tid] = fmaxf(s, 0.f);
    }
    __syncthreads();
    if (tid < 122) {
        float s = 0.f;
        #pragma unroll
        for (int j = 0; j < 7; ++j) s += f2[tid * 7 + j] * y1[j];
        sey[b * 122 + tid] = 1.f / (1.f + expf(-s));
        ((float*)mean)[b * 122 + tid] = 0.f;   // ready for next tblock's accumulation
    }
}

// ---- Wt = conv11(Wt2(bf16), rot180(w1)^T)/121, 121 -> 1; tile stride 48 ----
__global__ __launch_bounds__(256) void k_wt(const ushortt* __restrict__ Wt2,
                                            const float* __restrict__ w1,
                                            float* __restrict__ out) {
    __shared__ float tile[26 * 48];
    int b = blockIdx.y;
    int ty0 = (blockIdx.x >> 4) * 16, tx0 = (blockIdx.x & 15) * 16;
    int tid = threadIdx.x;
    int tX = tid & 15, tY = tid >> 4;
    float acc = 0.f;
    for (int ic = 0; ic < 121; ++ic) {
        const ushortt* src = Wt2 + ((b * 121 + ic) << 16);
        for (int idx = tid; idx < 26 * 26; idx += 256) {
            int r = idx / 26, c = idx - r * 26;
            tile[r * 48 + c] = bf2f(src[(refl(ty0 + r - 5) << 8) + refl(tx0 + c - 5)]);
        }
        __syncthreads();
        const float* wr = w1 + ic * 121;
        #pragma unroll 1
        for (int ky = 0; ky < 11; ++ky) {
            #pragma unroll
            for (int kx = 0; kx < 11; ++kx)
                acc += wr[(10 - ky) * 11 + (10 - kx)] * tile[(tY + ky) * 48 + tX + kx];
        }
        __syncthreads();
    }
    out[(b << 16) + ((ty0 + tY) << 8) + tx0 + tX] = acc * (1.f / 121.f);
}

extern "C" void kernel_launch(void* const* d_in, const int* in_sizes, int n_in,
                              void* d_out, int out_size, void* d_ws, size_t ws_size,
                              hipStream_t stream) {
    const float* input = (const float*)d_in[0];
    const float* sigma = (const float*)d_in[1];
    const float* w1    = (const float*)d_in[2];
    const float* b1    = (const float*)d_in[3];
    const float* w2    = (const float*)d_in[4];
    const float* b2    = (const float*)d_in[5];
    const float* n1w   = (const float*)d_in[6];
    const float* n1b   = (const float*)d_in[7];
    const float* thw   = (const float*)d_in[8];
    const float* tdw   = (const float*)d_in[9];
    const float* fnw   = (const float*)d_in[10];
    const float* fnb   = (const float*)d_in[11];
    const float* pw    = (const float*)d_in[12];
    const float* se1f1 = (const float*)d_in[13];
    const float* se1f2 = (const float*)d_in[14];
    const float* se2f1 = (const float*)d_in[15];
    const float* se2f2 = (const float*)d_in[16];
    const float* c1w   = (const float*)d_in[17];
    const float* c1b   = (const float*)d_in[18];
    const float* c2w   = (const float*)d_in[19];
    const float* c2b   = (const float*)d_in[20];
    float* out = (float*)d_out;
    float* ws  = (float*)d_ws;

    const size_t T121 = 15859712, T122 = 15990784;
    float* Wx1f   = ws;
    float* bufBf  = Wx1f + T121;
    float* C      = bufBf + T121;
    float* D      = C + T122;
    float* means  = D + T122;
    float* sey    = means + 256;
    short* thwf   = (short*)(sey + 256);
    ushortt* Wx1   = (ushortt*)Wx1f;
    ushortt* bufB  = (ushortt*)bufBf;
    ushortt* o_bf  = (ushortt*)C;
    ushortt* out1_bf = (ushortt*)C;
    ushortt* temp_bf = (ushortt*)C;
    ushortt* v_bf  = (ushortt*)D;
    ushortt* z_bf  = (ushortt*)D;      // z lives in D (old c slot); v dead by then
    // park repacked weights in the dead upper halves (32 MB offset = 8M floats):
    short* WfA = (short*)(bufBf + 8388608);
    short* WfB = (short*)(Wx1f + 8388608);
    short* Wf3 = (short*)(C + 8388608);

    dim3 blk(256);
    const ushortt* UNUL = nullptr;
    float* FNUL = nullptr;

    k_init<<<dim3(58), blk, 0, stream>>>(w1, out, means);
    k_wrepack_thw<<<dim3(496), blk, 0, stream>>>(thw, thwf);
    k_conv11_1toC<<<dim3(256, 121, 2), blk, 0, stream>>>(input, w1, b1, Wx1);
    k_wrepack2<<<dim3(7936), blk, 0, stream>>>(w2, WfA, WfB);   // both layouts, one pass

    // ---- tblock 1 ----
    k_fsas_patch<<<dim3(1024, 2), blk, 0, stream>>>(input, Wx1, n1w, n1b, thwf, tdw, o_bf, v_bf);
    k_a_ln<<<dim3(256), blk, 0, stream>>>(o_bf, v_bf, fnw, fnb);
    k_pw_res<<<dim3(32, 16, 2), blk, 0, stream>>>(v_bf, pw, input, Wx1, out1_bf, means); // out1 -> C (+SE sums)
    k_wrepack3<<<dim3(576), blk, 0, stream>>>(c1w, Wf3);
    k_se_fc<<<dim3(2), blk, 0, stream>>>(means, se1f1, se1f2, sey);
    k_conv3_mfma<<<dim3(256, 2), blk, 0, stream>>>(out1_bf, Wf3, c1b, sey, sigma, Wx1, z_bf); // z1 -> D (fused soft)
    k_conv11_mfma<<<dim3(256, 2), blk, 0, stream>>>(z_bf, WfA, b2, 1.f, UNUL, bufB, FNUL);    // Wx2

    // ---- tblock 2 ----
    k_fsas_patch<<<dim3(1024, 2), blk, 0, stream>>>(input, bufB, n1w, n1b, thwf, tdw, o_bf, v_bf);
    k_a_ln<<<dim3(256), blk, 0, stream>>>(o_bf, v_bf, fnw, fnb);
    k_pw_res<<<dim3(32, 16, 2), blk, 0, stream>>>(v_bf, pw, input, bufB, out1_bf, means);
    k_wrepack3<<<dim3(576), blk, 0, stream>>>(c2w, Wf3);
    k_se_fc<<<dim3(2), blk, 0, stream>>>(means, se2f1, se2f2, sey);
    k_conv3_mfma<<<dim3(256, 2), blk, 0, stream>>>(out1_bf, Wf3, c2b, sey, sigma, bufB, z_bf); // z2 -> D (fused soft)

    // ---- tail (WfA/WfB both built up front) ----
    k_conv11_mfma<<<dim3(256, 2), blk, 0, stream>>>(z_bf, WfB, FNUL, 1.f / 121.f, UNUL, bufB, FNUL); // Wt2
    k_wt<<<dim3(256, 2), blk, 0, stream>>>(bufB, w1, out);                                           // Wt
    k_conv11_mfma<<<dim3(256, 2), blk, 0, stream>>>(Wx1, WfA, b2, 1.f, UNUL, temp_bf, FNUL);         // temp
    k_conv11_mfma<<<dim3(256, 2), blk, 0, stream>>>(temp_bf, WfB, FNUL, 1.f / 121.f, Wx1, (ushortt*)FNUL, out + 145713); // W2loss

    (void)in_sizes; (void)n_in; (void)out_size; (void)ws_size;
}